// Round 8
// baseline (223.775 us; speedup 1.0000x reference)
//
#include <hip/hip_runtime.h>
#include <hip/hip_bf16.h>
#include <math.h>

#define BATCH 64
#define HH 56
#define CH 96
#define HEADS 3
#define WIN 7
#define SHIFT 3
#define TOK 49
#define MLPH 384
#define SCALE 0.17677669529663687f  // 1/sqrt(32)

typedef short bf16x8 __attribute__((ext_vector_type(8)));
typedef float f32x4 __attribute__((ext_vector_type(4)));

#define MFMA(a, b, c) __builtin_amdgcn_mfma_f32_16x16x32_bf16((a), (b), (c), 0, 0, 0)
#define MEMFENCE() asm volatile("" ::: "memory")

__device__ __forceinline__ bf16x8 ldfrag(const __hip_bfloat16* p) {
    return *(const bf16x8*)p;
}
__device__ __forceinline__ unsigned short f2bf(float f) {
    __hip_bfloat16 h = __float2bfloat16(f);
    unsigned short u; __builtin_memcpy(&u, &h, 2); return u;
}

// ws layout: bf16 weights [0,110592): qkvw 288x96 | projw 96x96 @27648 | fc1w 384x96 @36864 | fc2w 96x384 @73728
// then float btab[4 cat][3 h][64 q][64 k] at byte offset 221184 (196608 B)
__global__ __launch_bounds__(256) void prep(
    const float* __restrict__ qkvw, const float* __restrict__ projw,
    const float* __restrict__ fc1w, const float* __restrict__ fc2w,
    const float* __restrict__ relb,
    __hip_bfloat16* __restrict__ wbf, float* __restrict__ btab)
{
    int i = blockIdx.x * 256 + threadIdx.x;
    if (i < 27648)        wbf[i] = __float2bfloat16(qkvw[i]);
    else if (i < 36864)   wbf[i] = __float2bfloat16(projw[i - 27648]);
    else if (i < 73728)   wbf[i] = __float2bfloat16(fc1w[i - 36864]);
    else if (i < 110592)  wbf[i] = __float2bfloat16(fc2w[i - 73728]);
    else {
        int j = i - 110592;                 // [0, 49152)
        int cat = j / 12288;
        int r = j - cat * 12288;
        int h = r >> 12;
        int r2 = r & 4095;
        int q = r2 >> 6, k = r2 & 63;       // q outer, k inner (float4 along k)
        float v;
        if (k >= TOK) v = -10000.f;         // kill pad-k columns in softmax
        else if (q >= TOK) v = 0.f;         // pad-q rows: don't care
        else {
            int qi = q / WIN, qj = q - qi * WIN;
            int ki = k / WIN, kj = k - ki * WIN;
            int ridx = (qi - ki + 6) * 13 + (qj - kj + 6);
            v = relb[ridx * HEADS + h];
            int rqh = (cat & 2) ? (qi < 4 ? 1 : 2) : 0;
            int rqw = (cat & 1) ? (qj < 4 ? 1 : 2) : 0;
            int rkh = (cat & 2) ? (ki < 4 ? 1 : 2) : 0;
            int rkw = (cat & 1) ? (kj < 4 ? 1 : 2) : 0;
            if (rqh * 3 + rqw != rkh * 3 + rkw) v -= 100.f;
        }
        btab[j] = v;
    }
}

__global__ __launch_bounds__(256) void swin_attn(
    const float* __restrict__ x,
    const float* __restrict__ n1w, const float* __restrict__ n1b,
    const __hip_bfloat16* __restrict__ wqkv, const float* __restrict__ qkvb,
    const float* __restrict__ btab,
    const __hip_bfloat16* __restrict__ wproj, const float* __restrict__ projb,
    float* __restrict__ out)
{
    // XL holds LN'd input for qkv, then is overwritten with attention output for proj.
    __shared__ __align__(16) __hip_bfloat16 XL[64][104];
    __shared__ __align__(16) __hip_bfloat16 Qf[64][104];
    __shared__ __align__(16) __hip_bfloat16 Kf[64][104];
    __shared__ __align__(16) __hip_bfloat16 Vt[96][72];    // V transposed: [d][tok]
    __shared__ __align__(16) __hip_bfloat16 Pw[4][16][72]; // per-wave P staging

    const int blk = blockIdx.x;
    const int b = blk >> 6, win = blk & 63;
    const int wi = win >> 3, wj = win & 7;
    const int cat = ((wi == 7) << 1) | (wj == 7);
    const int tid = threadIdx.x;
    const int lane = tid & 63, w = tid >> 6;
    const int lr = lane & 15, g = lane >> 4;
    const int k0 = g * 8;
    const size_t bbase = (size_t)b * (HH * HH * CH);

    // ---- LN1 + shifted-window gather (4 threads/row); zero pad rows ----
    {
        int r = tid >> 2, p = tid & 3;
        if (r < TOK) {
            int ti = r / WIN, tj = r - (r / WIN) * WIN;
            int ph = wi * WIN + ti + SHIFT; if (ph >= HH) ph -= HH;
            int pw = wj * WIN + tj + SHIFT; if (pw >= HH) pw -= HH;
            const float4* xr = (const float4*)(x + bbase + (size_t)(ph * HH + pw) * CH + p * 24);
            float v[24]; float s = 0.f, s2 = 0.f;
            #pragma unroll
            for (int i = 0; i < 6; ++i) {
                float4 f = xr[i];
                v[4*i] = f.x; v[4*i+1] = f.y; v[4*i+2] = f.z; v[4*i+3] = f.w;
            }
            #pragma unroll
            for (int i = 0; i < 24; ++i) { s += v[i]; s2 += v[i] * v[i]; }
            s  += __shfl_xor(s, 1);  s  += __shfl_xor(s, 2);
            s2 += __shfl_xor(s2, 1); s2 += __shfl_xor(s2, 2);
            float mu = s * (1.f / CH);
            float rstd = rsqrtf(s2 * (1.f / CH) - mu * mu + 1e-5f);
            #pragma unroll
            for (int i = 0; i < 24; ++i) {
                int c = p * 24 + i;
                XL[r][c] = __float2bfloat16((v[i] - mu) * rstd * n1w[c] + n1b[c]);
            }
        } else {
            #pragma unroll
            for (int i = 0; i < 24; ++i) XL[r][p * 24 + i] = __float2bfloat16(0.f);
        }
    }
    __syncthreads();

    // ---- qkv GEMM, D[channel][token]: A = weight rows, B = activation rows.
    //      Lane (lr,g) holds D[ch = n*16+4g+j][tok = tt*16+lr] -> ushort4 row stores. ----
    {
        bf16x8 Bx[4][3];
        #pragma unroll
        for (int tt = 0; tt < 4; ++tt)
            #pragma unroll
            for (int ks = 0; ks < 3; ++ks)
                Bx[tt][ks] = ldfrag(&XL[tt * 16 + lr][ks * 32 + k0]);
        #pragma unroll
        for (int nn = 0; nn < 5; ++nn) {
            int n = w + 4 * nn;
            if (n < 18) {
                const __hip_bfloat16* wp = wqkv + (n * 16 + lr) * CH + k0;
                bf16x8 Af[3];
                #pragma unroll
                for (int ks = 0; ks < 3; ++ks) Af[ks] = ldfrag(wp + ks * 32);
                f32x4 acc[4];
                #pragma unroll
                for (int tt = 0; tt < 4; ++tt) acc[tt] = (f32x4){0.f, 0.f, 0.f, 0.f};
                #pragma unroll
                for (int ks = 0; ks < 3; ++ks)
                    #pragma unroll
                    for (int tt = 0; tt < 4; ++tt)
                        acc[tt] = MFMA(Af[ks], Bx[tt][ks], acc[tt]);
                f32x4 b4 = *(const f32x4*)(qkvb + n * 16 + 4 * g);
                #pragma unroll
                for (int tt = 0; tt < 4; ++tt) {
                    int tokr = tt * 16 + lr;
                    if (n < 6) {
                        ushort4 u;
                        u.x = f2bf((acc[tt][0] + b4[0]) * SCALE);
                        u.y = f2bf((acc[tt][1] + b4[1]) * SCALE);
                        u.z = f2bf((acc[tt][2] + b4[2]) * SCALE);
                        u.w = f2bf((acc[tt][3] + b4[3]) * SCALE);
                        *(ushort4*)&Qf[tokr][n * 16 + 4 * g] = u;
                    } else if (n < 12) {
                        ushort4 u;
                        u.x = f2bf(acc[tt][0] + b4[0]);
                        u.y = f2bf(acc[tt][1] + b4[1]);
                        u.z = f2bf(acc[tt][2] + b4[2]);
                        u.w = f2bf(acc[tt][3] + b4[3]);
                        *(ushort4*)&Kf[tokr][(n - 6) * 16 + 4 * g] = u;
                    } else {
                        #pragma unroll
                        for (int j = 0; j < 4; ++j)
                            Vt[(n - 12) * 16 + 4 * g + j][tokr] =
                                __float2bfloat16(acc[tt][j] + b4[j]);
                    }
                }
            }
        }
    }
    __syncthreads();

    // ---- attention units: wave w handles qt=w for all 3 heads (unchanged from r7) ----
    for (int u = w; u < 12; u += 4) {
        int h = u >> 2, qt = u & 3;
        bf16x8 qfrag = ldfrag(&Qf[qt * 16 + lr][h * 32 + k0]);
        f32x4 s[4];
        #pragma unroll
        for (int kt = 0; kt < 4; ++kt) {
            f32x4 z = {0.f, 0.f, 0.f, 0.f};
            s[kt] = MFMA(ldfrag(&Kf[kt * 16 + lr][h * 32 + k0]), qfrag, z);
        }
        const float* bt = btab + (((cat * HEADS + h) << 12) | ((qt * 16 + lr) << 6));
        #pragma unroll
        for (int kt = 0; kt < 4; ++kt)
            s[kt] += *(const f32x4*)(bt + kt * 16 + 4 * g);
        float m = -1e30f;
        #pragma unroll
        for (int kt = 0; kt < 4; ++kt)
            #pragma unroll
            for (int j = 0; j < 4; ++j) m = fmaxf(m, s[kt][j]);
        m = fmaxf(m, __shfl_xor(m, 16));
        m = fmaxf(m, __shfl_xor(m, 32));
        float e[4][4]; float sum = 0.f;
        #pragma unroll
        for (int kt = 0; kt < 4; ++kt)
            #pragma unroll
            for (int j = 0; j < 4; ++j) { e[kt][j] = __expf(s[kt][j] - m); sum += e[kt][j]; }
        sum += __shfl_xor(sum, 16);
        sum += __shfl_xor(sum, 32);
        float inv = 1.f / sum;
        #pragma unroll
        for (int kt = 0; kt < 4; ++kt) {
            ushort2 p0, p1;
            p0.x = f2bf(e[kt][0] * inv); p0.y = f2bf(e[kt][1] * inv);
            p1.x = f2bf(e[kt][2] * inv); p1.y = f2bf(e[kt][3] * inv);
            *(ushort2*)&Pw[w][lr][kt * 16 + g * 4]     = p0;
            *(ushort2*)&Pw[w][lr][kt * 16 + g * 4 + 2] = p1;
        }
        MEMFENCE();   // Pw stores -> PV fragment loads (same-wave rows; r3-proven pattern)
        #pragma unroll
        for (int dt = 0; dt < 2; ++dt) {
            f32x4 o = {0.f, 0.f, 0.f, 0.f};
            #pragma unroll
            for (int ks = 0; ks < 2; ++ks) {
                bf16x8 pa = ldfrag(&Pw[w][lr][ks * 32 + k0]);
                bf16x8 vb = ldfrag(&Vt[h * 32 + dt * 16 + lr][ks * 32 + k0]);
                o = MFMA(pa, vb, o);
            }
            #pragma unroll
            for (int j = 0; j < 4; ++j)
                XL[qt * 16 + g * 4 + j][h * 32 + dt * 16 + lr] = __float2bfloat16(o[j]);
        }
    }
    __syncthreads();

    // ---- proj + residual + inverse-shift scatter, D[channel][token]:
    //      lane holds 4 consecutive channels of one token -> f32x4 global load+store ----
    {
        bf16x8 Bx[4][3];
        #pragma unroll
        for (int tt = 0; tt < 4; ++tt)
            #pragma unroll
            for (int ks = 0; ks < 3; ++ks)
                Bx[tt][ks] = ldfrag(&XL[tt * 16 + lr][ks * 32 + k0]);
        #pragma unroll
        for (int nn = 0; nn < 2; ++nn) {
            int n = w + 4 * nn;
            if (n < 6) {
                const __hip_bfloat16* wp = wproj + (n * 16 + lr) * CH + k0;
                bf16x8 Af[3];
                #pragma unroll
                for (int ks = 0; ks < 3; ++ks) Af[ks] = ldfrag(wp + ks * 32);
                f32x4 acc[4];
                #pragma unroll
                for (int tt = 0; tt < 4; ++tt) acc[tt] = (f32x4){0.f, 0.f, 0.f, 0.f};
                #pragma unroll
                for (int ks = 0; ks < 3; ++ks)
                    #pragma unroll
                    for (int tt = 0; tt < 4; ++tt)
                        acc[tt] = MFMA(Af[ks], Bx[tt][ks], acc[tt]);
                f32x4 b4 = *(const f32x4*)(projb + n * 16 + 4 * g);
                #pragma unroll
                for (int tt = 0; tt < 4; ++tt) {
                    int tokr = tt * 16 + lr;
                    if (tokr < TOK) {
                        int ti = tokr / WIN, tj = tokr - (tokr / WIN) * WIN;
                        int ph = wi * WIN + ti + SHIFT; if (ph >= HH) ph -= HH;
                        int pw = wj * WIN + tj + SHIFT; if (pw >= HH) pw -= HH;
                        size_t gi = bbase + (size_t)(ph * HH + pw) * CH + n * 16 + 4 * g;
                        f32x4 x4 = *(const f32x4*)(x + gi);
                        *(f32x4*)(out + gi) = x4 + acc[tt] + b4;
                    }
                }
            }
        }
    }
}

__global__ __launch_bounds__(256) void swin_mlp(
    float* __restrict__ out,
    const float* __restrict__ n2w, const float* __restrict__ n2b,
    const __hip_bfloat16* __restrict__ w1, const float* __restrict__ b1,
    const __hip_bfloat16* __restrict__ w2, const float* __restrict__ b2)
{
    __shared__ __align__(16) __hip_bfloat16 XL2[64][104];
    __shared__ __align__(16) __hip_bfloat16 Hs[64][200];   // one 192-col chunk of MLP hidden

    const int tid = threadIdx.x;
    const int lane = tid & 63, w = tid >> 6;
    const int lr = lane & 15, g = lane >> 4, k0 = g * 8;
    const size_t base = (size_t)blockIdx.x * 64 * CH;

    // ---- LN2 (4 threads/row) ----
    {
        int r = tid >> 2, p = tid & 3;
        const float4* xr = (const float4*)(out + base + (size_t)r * CH + p * 24);
        float v[24]; float s = 0.f, s2 = 0.f;
        #pragma unroll
        for (int i = 0; i < 6; ++i) {
            float4 f = xr[i];
            v[4*i] = f.x; v[4*i+1] = f.y; v[4*i+2] = f.z; v[4*i+3] = f.w;
        }
        #pragma unroll
        for (int i = 0; i < 24; ++i) { s += v[i]; s2 += v[i] * v[i]; }
        s  += __shfl_xor(s, 1);  s  += __shfl_xor(s, 2);
        s2 += __shfl_xor(s2, 1); s2 += __shfl_xor(s2, 2);
        float mu = s * (1.f / CH);
        float rstd = rsqrtf(s2 * (1.f / CH) - mu * mu + 1e-5f);
        #pragma unroll
        for (int i = 0; i < 24; ++i) {
            int c = p * 24 + i;
            XL2[r][c] = __float2bfloat16((v[i] - mu) * rstd * n2w[c] + n2b[c]);
        }
    }
    __syncthreads();

    // activation B-fragments (all token tiles), reused by fc1 across chunks
    bf16x8 Bx[4][3];
    #pragma unroll
    for (int tt = 0; tt < 4; ++tt)
        #pragma unroll
        for (int ks = 0; ks < 3; ++ks)
            Bx[tt][ks] = ldfrag(&XL2[tt * 16 + lr][ks * 32 + k0]);

    const int mh = w & 1, nh = w >> 1;
    f32x4 acc2[3][2];
    #pragma unroll
    for (int nt = 0; nt < 3; ++nt)
        #pragma unroll
        for (int mi = 0; mi < 2; ++mi) acc2[nt][mi] = (f32x4){0.f, 0.f, 0.f, 0.f};

    #pragma unroll
    for (int c = 0; c < 2; ++c) {
        // fc1 + sigmoid-GELU, D[ch][tok]: wave w does ch-tiles nl = w, w+4, w+8
        #pragma unroll
        for (int nn = 0; nn < 3; ++nn) {
            int nl = w + 4 * nn;
            int ncol = c * 192 + nl * 16;               // global fc1 output channel base
            const __hip_bfloat16* wp = w1 + (ncol + lr) * CH + k0;
            bf16x8 Af[3];
            #pragma unroll
            for (int ks = 0; ks < 3; ++ks) Af[ks] = ldfrag(wp + ks * 32);
            f32x4 acc[4];
            #pragma unroll
            for (int tt = 0; tt < 4; ++tt) acc[tt] = (f32x4){0.f, 0.f, 0.f, 0.f};
            #pragma unroll
            for (int ks = 0; ks < 3; ++ks)
                #pragma unroll
                for (int tt = 0; tt < 4; ++tt)
                    acc[tt] = MFMA(Af[ks], Bx[tt][ks], acc[tt]);
            f32x4 b4 = *(const f32x4*)(b1 + ncol + 4 * g);
            #pragma unroll
            for (int tt = 0; tt < 4; ++tt) {
                ushort4 u;
                #pragma unroll
                for (int j = 0; j < 4; ++j) {
                    float v = acc[tt][j] + b4[j];
                    float ge = v / (1.f + __expf(-1.702f * v));
                    ((unsigned short*)&u)[j] = f2bf(ge);
                }
                *(ushort4*)&Hs[tt * 16 + lr][nl * 16 + 4 * g] = u;
            }
        }
        __syncthreads();   // fc1 chunk visible to all waves
        // fc2 partial over this chunk's K=192, D[ch][tok]: 2x2 (tok-half x ch-half) split
        bf16x8 Hb[2][6];
        #pragma unroll
        for (int mi = 0; mi < 2; ++mi)
            #pragma unroll
            for (int k = 0; k < 6; ++k)
                Hb[mi][k] = ldfrag(&Hs[mh * 32 + mi * 16 + lr][k * 32 + k0]);
        #pragma unroll
        for (int nt = 0; nt < 3; ++nt) {
            const __hip_bfloat16* wp = w2 + (nh * 48 + nt * 16 + lr) * MLPH + c * 192 + k0;
            #pragma unroll
            for (int k = 0; k < 6; ++k) {
                bf16x8 Af = ldfrag(wp + k * 32);
                acc2[nt][0] = MFMA(Af, Hb[0][k], acc2[nt][0]);
                acc2[nt][1] = MFMA(Af, Hb[1][k], acc2[nt][1]);
            }
        }
        __syncthreads();   // fc2 reads done before next chunk's fc1 overwrites Hs
    }

    // ---- epilogue: residual RMW, f32x4 per (nt, mi) ----
    #pragma unroll
    for (int nt = 0; nt < 3; ++nt) {
        f32x4 b4 = *(const f32x4*)(b2 + nh * 48 + nt * 16 + 4 * g);
        #pragma unroll
        for (int mi = 0; mi < 2; ++mi) {
            int tok = mh * 32 + mi * 16 + lr;
            size_t gi = base + (size_t)tok * CH + nh * 48 + nt * 16 + 4 * g;
            f32x4 r4 = *(const f32x4*)(out + gi);
            *(f32x4*)(out + gi) = r4 + acc2[nt][mi] + b4;
        }
    }
}

extern "C" void kernel_launch(void* const* d_in, const int* in_sizes, int n_in,
                              void* d_out, int out_size, void* d_ws, size_t ws_size,
                              hipStream_t stream) {
    const float* x     = (const float*)d_in[0];
    const float* n1w   = (const float*)d_in[1];
    const float* n1b   = (const float*)d_in[2];
    const float* qkvw  = (const float*)d_in[3];
    const float* qkvb  = (const float*)d_in[4];
    const float* relb  = (const float*)d_in[5];
    const float* projw = (const float*)d_in[6];
    const float* projb = (const float*)d_in[7];
    const float* n2w   = (const float*)d_in[8];
    const float* n2b   = (const float*)d_in[9];
    const float* fc1w  = (const float*)d_in[10];
    const float* fc1b  = (const float*)d_in[11];
    const float* fc2w  = (const float*)d_in[12];
    const float* fc2b  = (const float*)d_in[13];
    float* out = (float*)d_out;

    __hip_bfloat16* wbf = (__hip_bfloat16*)d_ws;
    float* btab = (float*)((char*)d_ws + 221184);
    const __hip_bfloat16* wqkv  = wbf;
    const __hip_bfloat16* wproj = wbf + 27648;
    const __hip_bfloat16* wfc1  = wbf + 36864;
    const __hip_bfloat16* wfc2  = wbf + 73728;

    prep<<<624, 256, 0, stream>>>(qkvw, projw, fc1w, fc2w, relb, wbf, btab);
    swin_attn<<<BATCH * 64, 256, 0, stream>>>(
        x, n1w, n1b, wqkv, qkvb, btab, wproj, projb, out);
    swin_mlp<<<(BATCH * HH * HH) / 64, 256, 0, stream>>>(
        out, n2w, n2b, wfc1, fc1b, wfc2, fc2b);
}

// Round 9
// 196.021 us; speedup vs baseline: 1.1416x; 1.1416x over previous
//
#include <hip/hip_runtime.h>
#include <hip/hip_bf16.h>
#include <math.h>

#define BATCH 64
#define HH 56
#define CH 96
#define HEADS 3
#define WIN 7
#define SHIFT 3
#define TOK 49
#define MLPH 384
#define SCALE 0.17677669529663687f  // 1/sqrt(32)

typedef short bf16x8 __attribute__((ext_vector_type(8)));
typedef float f32x4 __attribute__((ext_vector_type(4)));

#define MFMA(a, b, c) __builtin_amdgcn_mfma_f32_16x16x32_bf16((a), (b), (c), 0, 0, 0)
#define MEMFENCE() asm volatile("" ::: "memory")

__device__ __forceinline__ bf16x8 ldfrag(const __hip_bfloat16* p) {
    return *(const bf16x8*)p;
}
__device__ __forceinline__ unsigned short f2bf(float f) {
    __hip_bfloat16 h = __float2bfloat16(f);
    unsigned short u; __builtin_memcpy(&u, &h, 2); return u;
}

// ws layout: bf16 weights [0,110592): qkvw 288x96 | projw 96x96 @27648 | fc1w 384x96 @36864 | fc2w 96x384 @73728
// then float btab[4 cat][3 h][64 q][64 k] at byte offset 221184 (196608 B)
__global__ __launch_bounds__(256) void prep(
    const float* __restrict__ qkvw, const float* __restrict__ projw,
    const float* __restrict__ fc1w, const float* __restrict__ fc2w,
    const float* __restrict__ relb,
    __hip_bfloat16* __restrict__ wbf, float* __restrict__ btab)
{
    int i = blockIdx.x * 256 + threadIdx.x;
    if (i < 27648)        wbf[i] = __float2bfloat16(qkvw[i]);
    else if (i < 36864)   wbf[i] = __float2bfloat16(projw[i - 27648]);
    else if (i < 73728)   wbf[i] = __float2bfloat16(fc1w[i - 36864]);
    else if (i < 110592)  wbf[i] = __float2bfloat16(fc2w[i - 73728]);
    else {
        int j = i - 110592;                 // [0, 49152)
        int cat = j / 12288;
        int r = j - cat * 12288;
        int h = r >> 12;
        int r2 = r & 4095;
        int q = r2 >> 6, k = r2 & 63;       // q outer, k inner (float4 along k)
        float v;
        if (k >= TOK) v = -10000.f;         // kill pad-k columns in softmax
        else if (q >= TOK) v = 0.f;         // pad-q rows: don't care
        else {
            int qi = q / WIN, qj = q - qi * WIN;
            int ki = k / WIN, kj = k - ki * WIN;
            int ridx = (qi - ki + 6) * 13 + (qj - kj + 6);
            v = relb[ridx * HEADS + h];
            int rqh = (cat & 2) ? (qi < 4 ? 1 : 2) : 0;
            int rqw = (cat & 1) ? (qj < 4 ? 1 : 2) : 0;
            int rkh = (cat & 2) ? (ki < 4 ? 1 : 2) : 0;
            int rkw = (cat & 1) ? (kj < 4 ? 1 : 2) : 0;
            if (rqh * 3 + rqw != rkh * 3 + rkw) v -= 100.f;
        }
        btab[j] = v;
    }
}

__global__ __launch_bounds__(256) void swin_attn(
    const float* __restrict__ x,
    const float* __restrict__ n1w, const float* __restrict__ n1b,
    const __hip_bfloat16* __restrict__ wqkv, const float* __restrict__ qkvb,
    const float* __restrict__ btab,
    const __hip_bfloat16* __restrict__ wproj, const float* __restrict__ projb,
    float* __restrict__ out)
{
    // XL holds LN'd input for qkv, then is overwritten with attention output for proj.
    __shared__ __align__(16) __hip_bfloat16 XL[64][104];
    __shared__ __align__(16) __hip_bfloat16 Qf[64][104];
    __shared__ __align__(16) __hip_bfloat16 Kf[64][104];
    __shared__ __align__(16) __hip_bfloat16 Vt[96][72];    // V transposed: [d][tok]
    __shared__ __align__(16) __hip_bfloat16 Pw[4][16][72]; // per-wave P staging

    const int blk = blockIdx.x;
    const int b = blk >> 6, win = blk & 63;
    const int wi = win >> 3, wj = win & 7;
    const int cat = ((wi == 7) << 1) | (wj == 7);
    const int tid = threadIdx.x;
    const int lane = tid & 63, w = tid >> 6;
    const int lr = lane & 15, g = lane >> 4;
    const int k0 = g * 8;
    const size_t bbase = (size_t)b * (HH * HH * CH);

    // ---- LN1 + shifted-window gather (4 threads/row); zero pad rows ----
    {
        int r = tid >> 2, p = tid & 3;
        if (r < TOK) {
            int ti = r / WIN, tj = r - (r / WIN) * WIN;
            int ph = wi * WIN + ti + SHIFT; if (ph >= HH) ph -= HH;
            int pw = wj * WIN + tj + SHIFT; if (pw >= HH) pw -= HH;
            const float4* xr = (const float4*)(x + bbase + (size_t)(ph * HH + pw) * CH + p * 24);
            float v[24]; float s = 0.f, s2 = 0.f;
            #pragma unroll
            for (int i = 0; i < 6; ++i) {
                float4 f = xr[i];
                v[4*i] = f.x; v[4*i+1] = f.y; v[4*i+2] = f.z; v[4*i+3] = f.w;
            }
            #pragma unroll
            for (int i = 0; i < 24; ++i) { s += v[i]; s2 += v[i] * v[i]; }
            s  += __shfl_xor(s, 1);  s  += __shfl_xor(s, 2);
            s2 += __shfl_xor(s2, 1); s2 += __shfl_xor(s2, 2);
            float mu = s * (1.f / CH);
            float rstd = rsqrtf(s2 * (1.f / CH) - mu * mu + 1e-5f);
            #pragma unroll
            for (int i = 0; i < 24; ++i) {
                int c = p * 24 + i;
                XL[r][c] = __float2bfloat16((v[i] - mu) * rstd * n1w[c] + n1b[c]);
            }
        } else {
            #pragma unroll
            for (int i = 0; i < 24; ++i) XL[r][p * 24 + i] = __float2bfloat16(0.f);
        }
    }
    __syncthreads();

    // ---- qkv GEMM, D[channel][token]: A = weight rows, B = activation rows.
    //      Lane (lr,g) holds D[ch = n*16+4g+j][tok = tt*16+lr] -> ushort4 row stores. ----
    {
        bf16x8 Bx[4][3];
        #pragma unroll
        for (int tt = 0; tt < 4; ++tt)
            #pragma unroll
            for (int ks = 0; ks < 3; ++ks)
                Bx[tt][ks] = ldfrag(&XL[tt * 16 + lr][ks * 32 + k0]);
        #pragma unroll
        for (int nn = 0; nn < 5; ++nn) {
            int n = w + 4 * nn;
            if (n < 18) {
                const __hip_bfloat16* wp = wqkv + (n * 16 + lr) * CH + k0;
                bf16x8 Af[3];
                #pragma unroll
                for (int ks = 0; ks < 3; ++ks) Af[ks] = ldfrag(wp + ks * 32);
                f32x4 acc[4];
                #pragma unroll
                for (int tt = 0; tt < 4; ++tt) acc[tt] = (f32x4){0.f, 0.f, 0.f, 0.f};
                #pragma unroll
                for (int ks = 0; ks < 3; ++ks)
                    #pragma unroll
                    for (int tt = 0; tt < 4; ++tt)
                        acc[tt] = MFMA(Af[ks], Bx[tt][ks], acc[tt]);
                f32x4 b4 = *(const f32x4*)(qkvb + n * 16 + 4 * g);
                #pragma unroll
                for (int tt = 0; tt < 4; ++tt) {
                    int tokr = tt * 16 + lr;
                    if (n < 6) {
                        ushort4 u;
                        u.x = f2bf((acc[tt][0] + b4[0]) * SCALE);
                        u.y = f2bf((acc[tt][1] + b4[1]) * SCALE);
                        u.z = f2bf((acc[tt][2] + b4[2]) * SCALE);
                        u.w = f2bf((acc[tt][3] + b4[3]) * SCALE);
                        *(ushort4*)&Qf[tokr][n * 16 + 4 * g] = u;
                    } else if (n < 12) {
                        ushort4 u;
                        u.x = f2bf(acc[tt][0] + b4[0]);
                        u.y = f2bf(acc[tt][1] + b4[1]);
                        u.z = f2bf(acc[tt][2] + b4[2]);
                        u.w = f2bf(acc[tt][3] + b4[3]);
                        *(ushort4*)&Kf[tokr][(n - 6) * 16 + 4 * g] = u;
                    } else {
                        #pragma unroll
                        for (int j = 0; j < 4; ++j)
                            Vt[(n - 12) * 16 + 4 * g + j][tokr] =
                                __float2bfloat16(acc[tt][j] + b4[j]);
                    }
                }
            }
        }
    }
    __syncthreads();

    // ---- attention units: wave w handles qt=w for all 3 heads ----
    for (int u = w; u < 12; u += 4) {
        int h = u >> 2, qt = u & 3;
        bf16x8 qfrag = ldfrag(&Qf[qt * 16 + lr][h * 32 + k0]);
        f32x4 s[4];
        #pragma unroll
        for (int kt = 0; kt < 4; ++kt) {
            f32x4 z = {0.f, 0.f, 0.f, 0.f};
            s[kt] = MFMA(ldfrag(&Kf[kt * 16 + lr][h * 32 + k0]), qfrag, z);
        }
        const float* bt = btab + (((cat * HEADS + h) << 12) | ((qt * 16 + lr) << 6));
        #pragma unroll
        for (int kt = 0; kt < 4; ++kt)
            s[kt] += *(const f32x4*)(bt + kt * 16 + 4 * g);
        float m = -1e30f;
        #pragma unroll
        for (int kt = 0; kt < 4; ++kt)
            #pragma unroll
            for (int j = 0; j < 4; ++j) m = fmaxf(m, s[kt][j]);
        m = fmaxf(m, __shfl_xor(m, 16));
        m = fmaxf(m, __shfl_xor(m, 32));
        float e[4][4]; float sum = 0.f;
        #pragma unroll
        for (int kt = 0; kt < 4; ++kt)
            #pragma unroll
            for (int j = 0; j < 4; ++j) { e[kt][j] = __expf(s[kt][j] - m); sum += e[kt][j]; }
        sum += __shfl_xor(sum, 16);
        sum += __shfl_xor(sum, 32);
        float inv = 1.f / sum;
        #pragma unroll
        for (int kt = 0; kt < 4; ++kt) {
            ushort2 p0, p1;
            p0.x = f2bf(e[kt][0] * inv); p0.y = f2bf(e[kt][1] * inv);
            p1.x = f2bf(e[kt][2] * inv); p1.y = f2bf(e[kt][3] * inv);
            *(ushort2*)&Pw[w][lr][kt * 16 + g * 4]     = p0;
            *(ushort2*)&Pw[w][lr][kt * 16 + g * 4 + 2] = p1;
        }
        MEMFENCE();   // Pw stores -> PV fragment loads (same-wave rows; r3-proven pattern)
        #pragma unroll
        for (int dt = 0; dt < 2; ++dt) {
            f32x4 o = {0.f, 0.f, 0.f, 0.f};
            #pragma unroll
            for (int ks = 0; ks < 2; ++ks) {
                bf16x8 pa = ldfrag(&Pw[w][lr][ks * 32 + k0]);
                bf16x8 vb = ldfrag(&Vt[h * 32 + dt * 16 + lr][ks * 32 + k0]);
                o = MFMA(pa, vb, o);
            }
            #pragma unroll
            for (int j = 0; j < 4; ++j)
                XL[qt * 16 + g * 4 + j][h * 32 + dt * 16 + lr] = __float2bfloat16(o[j]);
        }
    }
    __syncthreads();

    // ---- proj + residual + inverse-shift scatter, D[channel][token]:
    //      lane holds 4 consecutive channels of one token -> f32x4 global load+store ----
    {
        bf16x8 Bx[4][3];
        #pragma unroll
        for (int tt = 0; tt < 4; ++tt)
            #pragma unroll
            for (int ks = 0; ks < 3; ++ks)
                Bx[tt][ks] = ldfrag(&XL[tt * 16 + lr][ks * 32 + k0]);
        #pragma unroll
        for (int nn = 0; nn < 2; ++nn) {
            int n = w + 4 * nn;
            if (n < 6) {
                const __hip_bfloat16* wp = wproj + (n * 16 + lr) * CH + k0;
                bf16x8 Af[3];
                #pragma unroll
                for (int ks = 0; ks < 3; ++ks) Af[ks] = ldfrag(wp + ks * 32);
                f32x4 acc[4];
                #pragma unroll
                for (int tt = 0; tt < 4; ++tt) acc[tt] = (f32x4){0.f, 0.f, 0.f, 0.f};
                #pragma unroll
                for (int ks = 0; ks < 3; ++ks)
                    #pragma unroll
                    for (int tt = 0; tt < 4; ++tt)
                        acc[tt] = MFMA(Af[ks], Bx[tt][ks], acc[tt]);
                f32x4 b4 = *(const f32x4*)(projb + n * 16 + 4 * g);
                #pragma unroll
                for (int tt = 0; tt < 4; ++tt) {
                    int tokr = tt * 16 + lr;
                    if (tokr < TOK) {
                        int ti = tokr / WIN, tj = tokr - (tokr / WIN) * WIN;
                        int ph = wi * WIN + ti + SHIFT; if (ph >= HH) ph -= HH;
                        int pw = wj * WIN + tj + SHIFT; if (pw >= HH) pw -= HH;
                        size_t gi = bbase + (size_t)(ph * HH + pw) * CH + n * 16 + 4 * g;
                        f32x4 x4 = *(const f32x4*)(x + gi);
                        *(f32x4*)(out + gi) = x4 + acc[tt] + b4;
                    }
                }
            }
        }
    }
}

__global__ __launch_bounds__(256) void swin_mlp(
    float* __restrict__ out,
    const float* __restrict__ n2w, const float* __restrict__ n2b,
    const __hip_bfloat16* __restrict__ w1, const float* __restrict__ b1,
    const __hip_bfloat16* __restrict__ w2, const float* __restrict__ b2)
{
    __shared__ __align__(16) __hip_bfloat16 XL2[64][104];
    __shared__ __align__(16) __hip_bfloat16 Hs[64][200];   // one 192-col chunk of MLP hidden

    const int tid = threadIdx.x;
    const int lane = tid & 63, w = tid >> 6;
    const int lr = lane & 15, g = lane >> 4, k0 = g * 8;
    const size_t base = (size_t)blockIdx.x * 64 * CH;

    // ---- LN2 (4 threads/row) ----
    {
        int r = tid >> 2, p = tid & 3;
        const float4* xr = (const float4*)(out + base + (size_t)r * CH + p * 24);
        float v[24]; float s = 0.f, s2 = 0.f;
        #pragma unroll
        for (int i = 0; i < 6; ++i) {
            float4 f = xr[i];
            v[4*i] = f.x; v[4*i+1] = f.y; v[4*i+2] = f.z; v[4*i+3] = f.w;
        }
        #pragma unroll
        for (int i = 0; i < 24; ++i) { s += v[i]; s2 += v[i] * v[i]; }
        s  += __shfl_xor(s, 1);  s  += __shfl_xor(s, 2);
        s2 += __shfl_xor(s2, 1); s2 += __shfl_xor(s2, 2);
        float mu = s * (1.f / CH);
        float rstd = rsqrtf(s2 * (1.f / CH) - mu * mu + 1e-5f);
        #pragma unroll
        for (int i = 0; i < 24; ++i) {
            int c = p * 24 + i;
            XL2[r][c] = __float2bfloat16((v[i] - mu) * rstd * n2w[c] + n2b[c]);
        }
    }
    __syncthreads();

    // ---- fc1/fc2 over 2 K-chunks of 192 (r7-proven structure) ----
    bf16x8 A[4][3];
    #pragma unroll
    for (int mt = 0; mt < 4; ++mt)
        #pragma unroll
        for (int ks = 0; ks < 3; ++ks)
            A[mt][ks] = ldfrag(&XL2[mt * 16 + lr][ks * 32 + k0]);

    const int mh = w & 1, nh = w >> 1;
    f32x4 acc2[3][2];
    #pragma unroll
    for (int nt = 0; nt < 3; ++nt)
        #pragma unroll
        for (int mi = 0; mi < 2; ++mi) acc2[nt][mi] = (f32x4){0.f, 0.f, 0.f, 0.f};

    #pragma unroll
    for (int c = 0; c < 2; ++c) {
        // fc1 + sigmoid-GELU: 12 local n-tiles, wave w does nl = w, w+4, w+8
        #pragma unroll
        for (int nn = 0; nn < 3; ++nn) {
            int nl = w + 4 * nn;
            int ncol = c * 192 + nl * 16 + lr;          // global fc1 output row
            const __hip_bfloat16* wb = w1 + ncol * CH + k0;
            f32x4 acc[4];
            #pragma unroll
            for (int mt = 0; mt < 4; ++mt) acc[mt] = (f32x4){0.f, 0.f, 0.f, 0.f};
            #pragma unroll
            for (int ks = 0; ks < 3; ++ks) {
                bf16x8 bf = ldfrag(wb + ks * 32);
                #pragma unroll
                for (int mt = 0; mt < 4; ++mt) acc[mt] = MFMA(A[mt][ks], bf, acc[mt]);
            }
            float bias = b1[ncol];
            #pragma unroll
            for (int mt = 0; mt < 4; ++mt)
                #pragma unroll
                for (int j = 0; j < 4; ++j) {
                    float v = acc[mt][j] + bias;
                    float ge = v / (1.f + __expf(-1.702f * v));
                    Hs[mt * 16 + g * 4 + j][nl * 16 + lr] = __float2bfloat16(ge);
                }
        }
        __syncthreads();   // fc1 chunk visible to all waves
        // fc2 partial over this chunk's K=192: 2x2 (M-half x N-half) wave split
        #pragma unroll
        for (int k = 0; k < 6; ++k) {
            bf16x8 a0 = ldfrag(&Hs[mh * 32 + lr][k * 32 + k0]);
            bf16x8 a1 = ldfrag(&Hs[mh * 32 + 16 + lr][k * 32 + k0]);
            #pragma unroll
            for (int nt = 0; nt < 3; ++nt) {
                bf16x8 bf = ldfrag(w2 + (nh * 48 + nt * 16 + lr) * MLPH + c * 192 + k * 32 + k0);
                acc2[nt][0] = MFMA(a0, bf, acc2[nt][0]);
                acc2[nt][1] = MFMA(a1, bf, acc2[nt][1]);
            }
        }
        __syncthreads();   // fc2 reads done before next chunk's fc1 overwrites Hs
    }

    // ---- epilogue: residual RMW ----
    #pragma unroll
    for (int nt = 0; nt < 3; ++nt) {
        int col = nh * 48 + nt * 16 + lr;
        float bias = b2[col];
        #pragma unroll
        for (int mi = 0; mi < 2; ++mi)
            #pragma unroll
            for (int j = 0; j < 4; ++j) {
                int tok = mh * 32 + mi * 16 + g * 4 + j;
                size_t gi = base + (size_t)tok * CH + col;
                out[gi] += acc2[nt][mi][j] + bias;
            }
    }
}

extern "C" void kernel_launch(void* const* d_in, const int* in_sizes, int n_in,
                              void* d_out, int out_size, void* d_ws, size_t ws_size,
                              hipStream_t stream) {
    const float* x     = (const float*)d_in[0];
    const float* n1w   = (const float*)d_in[1];
    const float* n1b   = (const float*)d_in[2];
    const float* qkvw  = (const float*)d_in[3];
    const float* qkvb  = (const float*)d_in[4];
    const float* relb  = (const float*)d_in[5];
    const float* projw = (const float*)d_in[6];
    const float* projb = (const float*)d_in[7];
    const float* n2w   = (const float*)d_in[8];
    const float* n2b   = (const float*)d_in[9];
    const float* fc1w  = (const float*)d_in[10];
    const float* fc1b  = (const float*)d_in[11];
    const float* fc2w  = (const float*)d_in[12];
    const float* fc2b  = (const float*)d_in[13];
    float* out = (float*)d_out;

    __hip_bfloat16* wbf = (__hip_bfloat16*)d_ws;
    float* btab = (float*)((char*)d_ws + 221184);
    const __hip_bfloat16* wqkv  = wbf;
    const __hip_bfloat16* wproj = wbf + 27648;
    const __hip_bfloat16* wfc1  = wbf + 36864;
    const __hip_bfloat16* wfc2  = wbf + 73728;

    prep<<<624, 256, 0, stream>>>(qkvw, projw, fc1w, fc2w, relb, wbf, btab);
    swin_attn<<<BATCH * 64, 256, 0, stream>>>(
        x, n1w, n1b, wqkv, qkvb, btab, wproj, projb, out);
    swin_mlp<<<(BATCH * HH * HH) / 64, 256, 0, stream>>>(
        out, n2w, n2b, wfc1, fc1b, wfc2, fc2b);
}